// Round 6
// baseline (499.280 us; speedup 1.0000x reference)
//
#include <hip/hip_runtime.h>

#define N_NODES 100000
#define N_EDGES 1250000
#define DIM 64
#define EDGE_DIM 10
#define BN_EPS 1e-5f

#define SCAN_CHUNK 1024
#define NB_SCAN ((N_NODES + SCAN_CHUNK - 1) / SCAN_CHUNK)   // 98

// workspace layout (int units). deg+sums adjacent -> one memset.
#define DEG_OFF    0
#define SUMS_OFF_I (DEG_OFF + N_NODES)        // 256 floats
#define OFFS_OFF   (SUMS_OFF_I + 256)
#define CUR_OFF    (OFFS_OFF + N_NODES)
#define BSUM_OFF   (CUR_OFF + N_NODES)
#define REC_OFF    (BSUM_OFF + 128)
// fast: records = 6 dwords/edge {src, w0..w4 packed bf16} at CSR slot (24 B)
// slow: records = 2 dwords/edge {src, e}
// xh (bf16 x copy) follows records in both modes.
// NOTE: fp32 aggregate is staged in the OUTPUT buffer (same size) -> no extra ws.

__device__ __forceinline__ unsigned f2bf(float f) {
    unsigned b = __float_as_uint(f);
    return (b + 0x7FFFu + ((b >> 16) & 1u)) >> 16;   // RTNE
}

// -----------------------------------------------------------------------------
// prep: x -> bf16 copy (vectorized) + degree histogram
// -----------------------------------------------------------------------------
extern "C" __global__ __launch_bounds__(256)
void prep_kernel(const float* __restrict__ x, unsigned short* __restrict__ xh,
                 const int* __restrict__ ei, int* __restrict__ deg)
{
    int t = blockIdx.x * 256 + threadIdx.x;
    int stride = gridDim.x * 256;
    for (int i = t; i < N_NODES * DIM / 4; i += stride) {
        float4 v = ((const float4*)x)[i];
        uint2 p;
        p.x = f2bf(v.x) | (f2bf(v.y) << 16);
        p.y = f2bf(v.z) | (f2bf(v.w) << 16);
        ((uint2*)xh)[i] = p;
    }
    for (int e = t; e < N_EDGES; e += stride) {
        unsigned d = (unsigned)ei[N_EDGES + e];
        d = d < N_NODES ? d : (N_NODES - 1);
        atomicAdd(&deg[d], 1);
    }
}

// -----------------------------------------------------------------------------
// scan (3 small kernels)
// -----------------------------------------------------------------------------
extern "C" __global__ __launch_bounds__(256)
void scan_bsum_kernel(const int* __restrict__ deg, int* __restrict__ bsum)
{
    __shared__ int sw[4];
    int tid = threadIdx.x;
    int base = blockIdx.x * SCAN_CHUNK + tid * 4;
    int s = 0;
    #pragma unroll
    for (int j = 0; j < 4; ++j) {
        int idx = base + j;
        if (idx < N_NODES) s += deg[idx];
    }
    #pragma unroll
    for (int m = 1; m < 64; m <<= 1) s += __shfl_xor(s, m, 64);
    if ((tid & 63) == 0) sw[tid >> 6] = s;
    __syncthreads();
    if (tid == 0) bsum[blockIdx.x] = sw[0] + sw[1] + sw[2] + sw[3];
}

extern "C" __global__ __launch_bounds__(128)
void scan_top_kernel(int* __restrict__ bsum)
{
    __shared__ int s[128];
    int tid = threadIdx.x;
    int v = (tid < NB_SCAN) ? bsum[tid] : 0;
    s[tid] = v;
    __syncthreads();
    #pragma unroll
    for (int off = 1; off < 128; off <<= 1) {
        int t = (tid >= off) ? s[tid - off] : 0;
        __syncthreads();
        s[tid] += t;
        __syncthreads();
    }
    if (tid < NB_SCAN) bsum[tid] = s[tid] - v;
}

extern "C" __global__ __launch_bounds__(256)
void scan_final_kernel(const int* __restrict__ deg, const int* __restrict__ bsum,
                       int* __restrict__ offs, int* __restrict__ cur)
{
    __shared__ int s[256];
    int tid = threadIdx.x;
    int base = blockIdx.x * SCAN_CHUNK + tid * 4;
    int d[4];
    #pragma unroll
    for (int j = 0; j < 4; ++j) {
        int idx = base + j;
        d[j] = (idx < N_NODES) ? deg[idx] : 0;
    }
    int tot = d[0] + d[1] + d[2] + d[3];
    s[tid] = tot;
    __syncthreads();
    #pragma unroll
    for (int off = 1; off < 256; off <<= 1) {
        int t = (tid >= off) ? s[tid - off] : 0;
        __syncthreads();
        s[tid] += t;
        __syncthreads();
    }
    int b = bsum[blockIdx.x] + s[tid] - tot;
    #pragma unroll
    for (int j = 0; j < 4; ++j) {
        int idx = base + j;
        if (idx < N_NODES) { offs[idx] = b; cur[idx] = b; }
        b += d[j];
    }
}

// -----------------------------------------------------------------------------
// scatter: one record per edge at its CSR slot.
// fast: {src, w0..w4} (24 B, 3x int2 stores); slow: {src, e} (8 B)
// -----------------------------------------------------------------------------
extern "C" __global__ __launch_bounds__(256)
void scatter_kernel(const int* __restrict__ ei, const float* __restrict__ ea,
                    int* __restrict__ cur, int* __restrict__ recs, int fast)
{
    int e = blockIdx.x * 256 + threadIdx.x;
    if (e >= N_EDGES) return;
    unsigned d = (unsigned)ei[N_EDGES + e];
    unsigned s = (unsigned)ei[e];
    d = d < N_NODES ? d : (N_NODES - 1);
    s = s < N_NODES ? s : (N_NODES - 1);
    int pos = atomicAdd(&cur[d], 1);
    if (fast) {
        const float* a = ea + (size_t)e * EDGE_DIM;
        unsigned w[5];
        #pragma unroll
        for (int k = 0; k < 5; ++k) {
            float2 p = *(const float2*)&a[2 * k];
            w[k] = f2bf(p.x) | (f2bf(p.y) << 16);
        }
        int2* r = (int2*)(recs + (size_t)pos * 6);
        r[0] = make_int2((int)s, (int)w[0]);
        r[1] = make_int2((int)w[1], (int)w[2]);
        r[2] = make_int2((int)w[3], (int)w[4]);
    } else {
        ((int2*)recs)[pos] = make_int2((int)s, e);
    }
}

// per-slot message compute: 5 attr dwords (10 bf16) x 4 features + x add + relu
#define SLOT_ACC(W0, Bv, Cv, Xv, MK)                                            \
    {                                                                           \
        float m0 = bias4.x, m1 = bias4.y, m2 = bias4.z, m3 = bias4.w;           \
        unsigned wd_; float a_;                                                 \
        wd_ = (unsigned)(W0);                                                   \
        a_ = __uint_as_float(wd_ << 16);                                        \
        m0 = fmaf(a_, wc[0].x, m0); m1 = fmaf(a_, wc[0].y, m1);                 \
        m2 = fmaf(a_, wc[0].z, m2); m3 = fmaf(a_, wc[0].w, m3);                 \
        a_ = __uint_as_float(wd_ & 0xFFFF0000u);                                \
        m0 = fmaf(a_, wc[1].x, m0); m1 = fmaf(a_, wc[1].y, m1);                 \
        m2 = fmaf(a_, wc[1].z, m2); m3 = fmaf(a_, wc[1].w, m3);                 \
        wd_ = (unsigned)(Bv).x;                                                 \
        a_ = __uint_as_float(wd_ << 16);                                        \
        m0 = fmaf(a_, wc[2].x, m0); m1 = fmaf(a_, wc[2].y, m1);                 \
        m2 = fmaf(a_, wc[2].z, m2); m3 = fmaf(a_, wc[2].w, m3);                 \
        a_ = __uint_as_float(wd_ & 0xFFFF0000u);                                \
        m0 = fmaf(a_, wc[3].x, m0); m1 = fmaf(a_, wc[3].y, m1);                 \
        m2 = fmaf(a_, wc[3].z, m2); m3 = fmaf(a_, wc[3].w, m3);                 \
        wd_ = (unsigned)(Bv).y;                                                 \
        a_ = __uint_as_float(wd_ << 16);                                        \
        m0 = fmaf(a_, wc[4].x, m0); m1 = fmaf(a_, wc[4].y, m1);                 \
        m2 = fmaf(a_, wc[4].z, m2); m3 = fmaf(a_, wc[4].w, m3);                 \
        a_ = __uint_as_float(wd_ & 0xFFFF0000u);                                \
        m0 = fmaf(a_, wc[5].x, m0); m1 = fmaf(a_, wc[5].y, m1);                 \
        m2 = fmaf(a_, wc[5].z, m2); m3 = fmaf(a_, wc[5].w, m3);                 \
        wd_ = (unsigned)(Cv).x;                                                 \
        a_ = __uint_as_float(wd_ << 16);                                        \
        m0 = fmaf(a_, wc[6].x, m0); m1 = fmaf(a_, wc[6].y, m1);                 \
        m2 = fmaf(a_, wc[6].z, m2); m3 = fmaf(a_, wc[6].w, m3);                 \
        a_ = __uint_as_float(wd_ & 0xFFFF0000u);                                \
        m0 = fmaf(a_, wc[7].x, m0); m1 = fmaf(a_, wc[7].y, m1);                 \
        m2 = fmaf(a_, wc[7].z, m2); m3 = fmaf(a_, wc[7].w, m3);                 \
        wd_ = (unsigned)(Cv).y;                                                 \
        a_ = __uint_as_float(wd_ << 16);                                        \
        m0 = fmaf(a_, wc[8].x, m0); m1 = fmaf(a_, wc[8].y, m1);                 \
        m2 = fmaf(a_, wc[8].z, m2); m3 = fmaf(a_, wc[8].w, m3);                 \
        a_ = __uint_as_float(wd_ & 0xFFFF0000u);                                \
        m0 = fmaf(a_, wc[9].x, m0); m1 = fmaf(a_, wc[9].y, m1);                 \
        m2 = fmaf(a_, wc[9].z, m2); m3 = fmaf(a_, wc[9].w, m3);                 \
        float x0_ = __uint_as_float(((unsigned)(Xv).x) << 16);                  \
        float x1_ = __uint_as_float(((unsigned)(Xv).x) & 0xFFFF0000u);          \
        float x2_ = __uint_as_float(((unsigned)(Xv).y) << 16);                  \
        float x3_ = __uint_as_float(((unsigned)(Xv).y) & 0xFFFF0000u);          \
        float c0_ = fmaxf(m0 + x0_, 0.0f);                                      \
        float c1_ = fmaxf(m1 + x1_, 0.0f);                                      \
        float c2_ = fmaxf(m2 + x2_, 0.0f);                                      \
        float c3_ = fmaxf(m3 + x3_, 0.0f);                                      \
        ax += (MK) ? c0_ : 0.0f; ay += (MK) ? c1_ : 0.0f;                       \
        az += (MK) ? c2_ : 0.0f; aw += (MK) ? c3_ : 0.0f;                       \
    }

// -----------------------------------------------------------------------------
// aggregation kernel: LDS-FREE, 2 nodes per wave, quarter-wave mapping.
// Writes fp32 aggregate (x_v + sum msgs) into the OUTPUT buffer.
// -----------------------------------------------------------------------------
extern "C" __global__ __launch_bounds__(256)
void aggr_kernel(const unsigned short* __restrict__ xh,
                 const float* __restrict__ ea,
                 const float* __restrict__ We,
                 const float* __restrict__ be,
                 const int* __restrict__ offs,
                 const int* __restrict__ cur,
                 const int* __restrict__ recs,
                 float* __restrict__ aggr,
                 int fast)
{
    int tid  = threadIdx.x;
    int lane = tid & 63;
    int wv   = tid >> 6;
    int fq   = lane & 15;
    int q    = lane >> 4;

    float4 wc[EDGE_DIM];
    #pragma unroll
    for (int k = 0; k < EDGE_DIM; ++k)
        wc[k] = *(const float4*)&We[k * DIM + 4 * fq];
    float4 bias4 = *(const float4*)&be[4 * fq];

    const uint2* xq2 = (const uint2*)xh;
    const int2*  rc2 = (const int2*)recs;

    #pragma unroll 1
    for (int t = 0; t < 2; ++t) {
        int v = blockIdx.x * 8 + wv * 2 + t;
        if (v >= N_NODES) break;
        uint2 sx = xq2[(unsigned)v * 16u + (unsigned)fq];   // self row, early
        int stt = __builtin_amdgcn_readfirstlane(offs[v]);
        int end = __builtin_amdgcn_readfirstlane(cur[v]);
        float ax = 0.f, ay = 0.f, az = 0.f, aw = 0.f;
        int ng = (end - stt + 15) >> 4;
        if (fast) {
            #pragma unroll 1
            for (int g = 0; g < ng; ++g) {
                int i0e = stt + g * 16;
                int e1  = end - 1;
                int s0 = i0e + q, s1 = s0 + 4, s2 = s0 + 8, s3 = s0 + 12;
                int c0 = 3 * min(s0, e1), c1 = 3 * min(s1, e1);
                int c2 = 3 * min(s2, e1), c3 = 3 * min(s3, e1);
                int2 A0 = rc2[c0],     A1 = rc2[c1];
                int2 A2 = rc2[c2],     A3 = rc2[c3];
                int2 B0 = rc2[c0 + 1], C0 = rc2[c0 + 2];
                int2 B1 = rc2[c1 + 1], C1 = rc2[c1 + 2];
                int2 B2 = rc2[c2 + 1], C2 = rc2[c2 + 2];
                int2 B3 = rc2[c3 + 1], C3 = rc2[c3 + 2];
                unsigned u0 = (unsigned)A0.x; u0 = u0 < N_NODES ? u0 : 0u;
                unsigned u1 = (unsigned)A1.x; u1 = u1 < N_NODES ? u1 : 0u;
                unsigned u2 = (unsigned)A2.x; u2 = u2 < N_NODES ? u2 : 0u;
                unsigned u3 = (unsigned)A3.x; u3 = u3 < N_NODES ? u3 : 0u;
                uint2 X0 = xq2[u0 * 16u + (unsigned)fq];
                uint2 X1 = xq2[u1 * 16u + (unsigned)fq];
                uint2 X2 = xq2[u2 * 16u + (unsigned)fq];
                uint2 X3 = xq2[u3 * 16u + (unsigned)fq];
                SLOT_ACC(A0.y, B0, C0, X0, s0 < end);
                SLOT_ACC(A1.y, B1, C1, X1, s1 < end);
                SLOT_ACC(A2.y, B2, C2, X2, s2 < end);
                SLOT_ACC(A3.y, B3, C3, X3, s3 < end);
            }
        } else {
            #pragma unroll 1
            for (int g = 0; g < ng; ++g) {
                int i0e = stt + g * 16;
                int e1  = end - 1;
                int s0 = i0e + q, s1 = s0 + 4, s2 = s0 + 8, s3 = s0 + 12;
                int2 A0 = ((const int2*)recs)[min(s0, e1)];
                int2 A1 = ((const int2*)recs)[min(s1, e1)];
                int2 A2 = ((const int2*)recs)[min(s2, e1)];
                int2 A3 = ((const int2*)recs)[min(s3, e1)];
                unsigned u0 = (unsigned)A0.x; u0 = u0 < N_NODES ? u0 : 0u;
                unsigned u1 = (unsigned)A1.x; u1 = u1 < N_NODES ? u1 : 0u;
                unsigned u2 = (unsigned)A2.x; u2 = u2 < N_NODES ? u2 : 0u;
                unsigned u3 = (unsigned)A3.x; u3 = u3 < N_NODES ? u3 : 0u;
                uint2 X0 = xq2[u0 * 16u + (unsigned)fq];
                uint2 X1 = xq2[u1 * 16u + (unsigned)fq];
                uint2 X2 = xq2[u2 * 16u + (unsigned)fq];
                uint2 X3 = xq2[u3 * 16u + (unsigned)fq];
                #pragma unroll
                for (int p = 0; p < 4; ++p) {
                    int sl = p == 0 ? s0 : p == 1 ? s1 : p == 2 ? s2 : s3;
                    unsigned ue = (unsigned)(p == 0 ? A0.y : p == 1 ? A1.y :
                                             p == 2 ? A2.y : A3.y);
                    ue = ue < N_EDGES ? ue : 0u;
                    uint2 Xv = p == 0 ? X0 : p == 1 ? X1 : p == 2 ? X2 : X3;
                    const float* a = ea + (size_t)ue * EDGE_DIM;
                    float m0 = bias4.x, m1 = bias4.y, m2 = bias4.z, m3 = bias4.w;
                    #pragma unroll
                    for (int k = 0; k < EDGE_DIM; ++k) {
                        float av = a[k];
                        m0 = fmaf(av, wc[k].x, m0);
                        m1 = fmaf(av, wc[k].y, m1);
                        m2 = fmaf(av, wc[k].z, m2);
                        m3 = fmaf(av, wc[k].w, m3);
                    }
                    float x0_ = __uint_as_float(Xv.x << 16);
                    float x1_ = __uint_as_float(Xv.x & 0xFFFF0000u);
                    float x2_ = __uint_as_float(Xv.y << 16);
                    float x3_ = __uint_as_float(Xv.y & 0xFFFF0000u);
                    bool mk = sl < end;
                    ax += mk ? fmaxf(m0 + x0_, 0.f) : 0.f;
                    ay += mk ? fmaxf(m1 + x1_, 0.f) : 0.f;
                    az += mk ? fmaxf(m2 + x2_, 0.f) : 0.f;
                    aw += mk ? fmaxf(m3 + x3_, 0.f) : 0.f;
                }
            }
        }
        // reduce across 4 quarters
        ax += __shfl_xor(ax, 16, 64); ax += __shfl_xor(ax, 32, 64);
        ay += __shfl_xor(ay, 16, 64); ay += __shfl_xor(ay, 32, 64);
        az += __shfl_xor(az, 16, 64); az += __shfl_xor(az, 32, 64);
        aw += __shfl_xor(aw, 16, 64); aw += __shfl_xor(aw, 32, 64);
        ax += __uint_as_float(sx.x << 16);
        ay += __uint_as_float(sx.x & 0xFFFF0000u);
        az += __uint_as_float(sx.y << 16);
        aw += __uint_as_float(sx.y & 0xFFFF0000u);
        if (q == 0)
            *(float4*)&aggr[(size_t)v * DIM + 4 * fq] =
                make_float4(ax, ay, az, aw);
    }
}

// -----------------------------------------------------------------------------
// MLP kernel v2: 256 threads, 64-node tile, 4 nodes x 4 feats per thread.
// Per k-step: 2x ds_read_b128 + 16 FMA (was 3 loads incl. 2 scalar + 8 FMA).
// No register cap -> deep unroll, many LDS loads in flight.
// -----------------------------------------------------------------------------
extern "C" __global__ __launch_bounds__(256)
void mlp_kernel(const float* __restrict__ W1,
                const float* __restrict__ b1,
                const float* __restrict__ W2,
                const float* __restrict__ b2,
                float* __restrict__ out,
                float* __restrict__ sums)
{
    __shared__ __align__(16) float sW[DIM * DIM];   // 16 KB, W1 then W2
    __shared__ __align__(16) float sT[DIM * 68];    // 17.4 KB

    int tid  = threadIdx.x;
    int lane = tid & 63;
    int base = blockIdx.x * 64;

    for (int i = tid; i < DIM * DIM; i += 256) sW[i] = W1[i];

    // stage aggregate tile transposed: thread covers node tid>>2, 16 feats
    {
        int nl = tid >> 2;
        int fo = (tid & 3) * 16;
        int v  = base + nl;
        v = v < N_NODES ? v : (N_NODES - 1);
        const float4* row = (const float4*)&out[(size_t)v * DIM + fo];
        float4 r0 = row[0], r1 = row[1], r2 = row[2], r3 = row[3];
        sT[(fo +  0) * 68 + nl] = r0.x;  sT[(fo +  1) * 68 + nl] = r0.y;
        sT[(fo +  2) * 68 + nl] = r0.z;  sT[(fo +  3) * 68 + nl] = r0.w;
        sT[(fo +  4) * 68 + nl] = r1.x;  sT[(fo +  5) * 68 + nl] = r1.y;
        sT[(fo +  6) * 68 + nl] = r1.z;  sT[(fo +  7) * 68 + nl] = r1.w;
        sT[(fo +  8) * 68 + nl] = r2.x;  sT[(fo +  9) * 68 + nl] = r2.y;
        sT[(fo + 10) * 68 + nl] = r2.z;  sT[(fo + 11) * 68 + nl] = r2.w;
        sT[(fo + 12) * 68 + nl] = r3.x;  sT[(fo + 13) * 68 + nl] = r3.y;
        sT[(fo + 14) * 68 + nl] = r3.z;  sT[(fo + 15) * 68 + nl] = r3.w;
    }
    __syncthreads();

    int i0 = (tid & 15) * 4;          // 4 nodes
    int j0 = (tid >> 4) * 4;          // 4 feats

    float acc1[4][4] = {};
    #pragma unroll 4
    for (int k = 0; k < DIM; ++k) {
        float4 av = *(const float4*)&sT[k * 68 + i0];
        float4 bw = *(const float4*)&sW[k * DIM + j0];
        float a4[4] = {av.x, av.y, av.z, av.w};
        float b4[4] = {bw.x, bw.y, bw.z, bw.w};
        #pragma unroll
        for (int a = 0; a < 4; ++a)
            #pragma unroll
            for (int b = 0; b < 4; ++b)
                acc1[a][b] = fmaf(a4[a], b4[b], acc1[a][b]);
    }
    __syncthreads();

    // refill weight buffer with W2 (all GEMM1 reads of sW are done)
    for (int i = tid; i < DIM * DIM; i += 256) sW[i] = W2[i];

    float4 b1v = *(const float4*)&b1[j0];
    float b1a[4] = {b1v.x, b1v.y, b1v.z, b1v.w};
    float tv[4][4];
    #pragma unroll
    for (int a = 0; a < 4; ++a)
        #pragma unroll
        for (int b = 0; b < 4; ++b)
            tv[a][b] = fmaxf(acc1[a][b] + b1a[b], 0.0f);

    #pragma unroll
    for (int b = 0; b < 4; ++b) {
        float4 w = make_float4(tv[0][b], tv[1][b], tv[2][b], tv[3][b]);
        *(float4*)&sT[(j0 + b) * 68 + i0] = w;
    }
    __syncthreads();

    float acc2[4][4] = {};
    #pragma unroll 4
    for (int k = 0; k < DIM; ++k) {
        float4 av = *(const float4*)&sT[k * 68 + i0];
        float4 bw = *(const float4*)&sW[k * DIM + j0];
        float a4[4] = {av.x, av.y, av.z, av.w};
        float b4[4] = {bw.x, bw.y, bw.z, bw.w};
        #pragma unroll
        for (int a = 0; a < 4; ++a)
            #pragma unroll
            for (int b = 0; b < 4; ++b)
                acc2[a][b] = fmaf(a4[a], b4[b], acc2[a][b]);
    }

    float4 b2v = *(const float4*)&b2[j0];
    float b2a[4] = {b2v.x, b2v.y, b2v.z, b2v.w};
    float ps[4] = {0.f, 0.f, 0.f, 0.f};
    float pq[4] = {0.f, 0.f, 0.f, 0.f};
    #pragma unroll
    for (int a = 0; a < 4; ++a) {
        int n = base + i0 + a;
        float r[4];
        #pragma unroll
        for (int b = 0; b < 4; ++b)
            r[b] = fmaxf(acc2[a][b] + b2a[b], 0.0f);
        if (n < N_NODES) {
            *(float4*)&out[(size_t)n * DIM + j0] =
                make_float4(r[0], r[1], r[2], r[3]);
            #pragma unroll
            for (int b = 0; b < 4; ++b) {
                ps[b] += r[b];
                pq[b] += r[b] * r[b];
            }
        }
    }

    #pragma unroll
    for (int m = 1; m < 16; m <<= 1) {
        #pragma unroll
        for (int b = 0; b < 4; ++b) {
            ps[b] += __shfl_xor(ps[b], m, 64);
            pq[b] += __shfl_xor(pq[b], m, 64);
        }
    }
    if ((lane & 15) == 0) {
        #pragma unroll
        for (int b = 0; b < 4; ++b) {
            unsafeAtomicAdd(&sums[j0 + b], ps[b]);
            unsafeAtomicAdd(&sums[64 + j0 + b], pq[b]);
        }
    }
}

// -----------------------------------------------------------------------------
// BN apply with inline stats
// -----------------------------------------------------------------------------
extern "C" __global__ __launch_bounds__(256)
void bn_apply_kernel(float* __restrict__ out, const float* __restrict__ sums,
                     const float* __restrict__ gamma, const float* __restrict__ beta)
{
    int j = blockIdx.x * 256 + threadIdx.x;
    int f0 = (j & 15) * 4;
    float4 s1 = *(const float4*)&sums[f0];
    float4 s2 = *(const float4*)&sums[64 + f0];
    float4 gm = *(const float4*)&gamma[f0];
    float4 bt = *(const float4*)&beta[f0];
    const float inv_n = 1.0f / (float)N_NODES;
    float4 sc, sh;
    {
        float m = s1.x * inv_n; float vv = fmaf(-m, m, s2.x * inv_n);
        sc.x = gm.x * rsqrtf(vv + BN_EPS); sh.x = fmaf(-m, sc.x, bt.x);
    }
    {
        float m = s1.y * inv_n; float vv = fmaf(-m, m, s2.y * inv_n);
        sc.y = gm.y * rsqrtf(vv + BN_EPS); sh.y = fmaf(-m, sc.y, bt.y);
    }
    {
        float m = s1.z * inv_n; float vv = fmaf(-m, m, s2.z * inv_n);
        sc.z = gm.z * rsqrtf(vv + BN_EPS); sh.z = fmaf(-m, sc.z, bt.z);
    }
    {
        float m = s1.w * inv_n; float vv = fmaf(-m, m, s2.w * inv_n);
        sc.w = gm.w * rsqrtf(vv + BN_EPS); sh.w = fmaf(-m, sc.w, bt.w);
    }
    float4 v = ((float4*)out)[j];
    v.x = fmaf(v.x, sc.x, sh.x);
    v.y = fmaf(v.y, sc.y, sh.y);
    v.z = fmaf(v.z, sc.z, sh.z);
    v.w = fmaf(v.w, sc.w, sh.w);
    ((float4*)out)[j] = v;
}

extern "C" void kernel_launch(void* const* d_in, const int* in_sizes, int n_in,
                              void* d_out, int out_size, void* d_ws, size_t ws_size,
                              hipStream_t stream)
{
    const float* x     = (const float*)d_in[0];
    const int*   ei    = (const int*)  d_in[1];
    const float* ea    = (const float*)d_in[2];
    const float* We    = (const float*)d_in[3];
    const float* be    = (const float*)d_in[4];
    const float* W1    = (const float*)d_in[5];
    const float* b1    = (const float*)d_in[6];
    const float* W2    = (const float*)d_in[7];
    const float* b2    = (const float*)d_in[8];
    const float* gamma = (const float*)d_in[9];
    const float* beta  = (const float*)d_in[10];

    float* out  = (float*)d_out;
    int*   wsi  = (int*)d_ws;
    int*   deg  = wsi + DEG_OFF;
    float* sums = (float*)(wsi + SUMS_OFF_I);
    int*   offs = wsi + OFFS_OFF;
    int*   cur  = wsi + CUR_OFF;
    int*   bsum = wsi + BSUM_OFF;
    int*   recs = wsi + REC_OFF;

    // fast mode: 24 B/edge records + xh (same verified layout/threshold)
    size_t need_fast = ((size_t)REC_OFF + 6u * N_EDGES + (size_t)N_NODES * DIM / 2) * 4u;
    int fast = (ws_size >= need_fast) ? 1 : 0;
    int rec_ints = fast ? 6 * N_EDGES : 2 * N_EDGES;
    unsigned short* xh = (unsigned short*)(wsi + REC_OFF + rec_ints);

    // zero deg + BN sums (adjacent) in one memset
    hipMemsetAsync(wsi, 0, (size_t)(N_NODES + 256) * sizeof(int), stream);

    prep_kernel<<<2048, 256, 0, stream>>>(x, xh, ei, deg);
    scan_bsum_kernel<<<NB_SCAN, 256, 0, stream>>>(deg, bsum);
    scan_top_kernel<<<1, 128, 0, stream>>>(bsum);
    scan_final_kernel<<<NB_SCAN, 256, 0, stream>>>(deg, bsum, offs, cur);
    scatter_kernel<<<(N_EDGES + 255) / 256, 256, 0, stream>>>(ei, ea, cur, recs, fast);

    // aggregation -> fp32 aggregate staged in `out`
    aggr_kernel<<<(N_NODES + 7) / 8, 256, 0, stream>>>(
        xh, ea, We, be, offs, cur, recs, out, fast);

    // MLP reads tile from `out`, overwrites `out`
    mlp_kernel<<<(N_NODES + 63) / 64, 256, 0, stream>>>(
        W1, b1, W2, b2, out, sums);

    bn_apply_kernel<<<(N_NODES * DIM / 4) / 256, 256, 0, stream>>>(out, sums, gamma, beta);
}

// Round 7
// 362.878 us; speedup vs baseline: 1.3759x; 1.3759x over previous
//
#include <hip/hip_runtime.h>

#define N_NODES 100000
#define N_EDGES 1250000
#define DIM 64
#define EDGE_DIM 10
#define BN_EPS 1e-5f

#define SCAN_CHUNK 1024
#define NB_SCAN ((N_NODES + SCAN_CHUNK - 1) / SCAN_CHUNK)   // 98

// workspace layout (int units). deg+sums adjacent -> one memset.
#define DEG_OFF    0
#define SUMS_OFF_I (DEG_OFF + N_NODES)        // 256 floats
#define OFFS_OFF   (SUMS_OFF_I + 256)
#define CUR_OFF    (OFFS_OFF + N_NODES)
#define BSUM_OFF   (CUR_OFF + N_NODES)
#define WH_OFF     (BSUM_OFF + 128)           // 4096 dwords: W1+W2 bf16 B-fragments
#define REC_OFF    (WH_OFF + 4096)
// fast: records = 6 dwords/edge {src, w0..w4 packed bf16} at CSR slot (24 B)
// slow: records = 2 dwords/edge {src, e}
// xh (bf16 x copy) follows records in both modes.
// fp32 aggregate is staged in the OUTPUT buffer (same size) -> no extra ws.

typedef __attribute__((ext_vector_type(8))) short short8v;   // 8 bf16 (4 VGPR)
typedef __attribute__((ext_vector_type(4))) float f32x4v;    // MFMA acc

__device__ __forceinline__ unsigned f2bf(float f) {
    unsigned b = __float_as_uint(f);
    return (b + 0x7FFFu + ((b >> 16) & 1u)) >> 16;   // RTNE
}

__device__ __forceinline__ short8v pack8(float4 a, float4 b) {
    short8v r;
    r[0] = (short)f2bf(a.x); r[1] = (short)f2bf(a.y);
    r[2] = (short)f2bf(a.z); r[3] = (short)f2bf(a.w);
    r[4] = (short)f2bf(b.x); r[5] = (short)f2bf(b.y);
    r[6] = (short)f2bf(b.z); r[7] = (short)f2bf(b.w);
    return r;
}

// -----------------------------------------------------------------------------
// prep: x -> bf16 copy (vectorized) + degree histogram
// -----------------------------------------------------------------------------
extern "C" __global__ __launch_bounds__(256)
void prep_kernel(const float* __restrict__ x, unsigned short* __restrict__ xh,
                 const int* __restrict__ ei, int* __restrict__ deg)
{
    int t = blockIdx.x * 256 + threadIdx.x;
    int stride = gridDim.x * 256;
    for (int i = t; i < N_NODES * DIM / 4; i += stride) {
        float4 v = ((const float4*)x)[i];
        uint2 p;
        p.x = f2bf(v.x) | (f2bf(v.y) << 16);
        p.y = f2bf(v.z) | (f2bf(v.w) << 16);
        ((uint2*)xh)[i] = p;
    }
    for (int e = t; e < N_EDGES; e += stride) {
        unsigned d = (unsigned)ei[N_EDGES + e];
        d = d < N_NODES ? d : (N_NODES - 1);
        atomicAdd(&deg[d], 1);
    }
}

// -----------------------------------------------------------------------------
// scan (3 small kernels). scan_bsum block 0 additionally packs W1/W2 into
// bf16 MFMA B-fragment order:
//   Wh[layer][kb][cg][lane][ip] (dword) = pack(W[k0][c], W[k0+1][c])
//   k0 = kb*32 + (lane>>4)*8 + 2*ip, c = cg*16 + (lane&15)
// -----------------------------------------------------------------------------
extern "C" __global__ __launch_bounds__(256)
void scan_bsum_kernel(const int* __restrict__ deg, int* __restrict__ bsum,
                      const float* __restrict__ W1, const float* __restrict__ W2,
                      unsigned* __restrict__ wh)
{
    __shared__ int sw[4];
    int tid = threadIdx.x;
    if (blockIdx.x == 0) {
        for (int g = tid; g < 4096; g += 256) {
            int layer = g >> 11;
            int r  = g & 2047;
            int kb = r >> 10;
            int r2 = r & 1023;
            int cg = r2 >> 8;
            int r3 = r2 & 255;
            int ln = r3 >> 2;
            int ip = r3 & 3;
            int k0 = kb * 32 + (ln >> 4) * 8 + 2 * ip;
            int c  = cg * 16 + (ln & 15);
            const float* W = layer ? W2 : W1;
            unsigned lo = f2bf(W[k0 * DIM + c]);
            unsigned hi = f2bf(W[(k0 + 1) * DIM + c]);
            wh[g] = lo | (hi << 16);
        }
    }
    int base = blockIdx.x * SCAN_CHUNK + tid * 4;
    int s = 0;
    #pragma unroll
    for (int j = 0; j < 4; ++j) {
        int idx = base + j;
        if (idx < N_NODES) s += deg[idx];
    }
    #pragma unroll
    for (int m = 1; m < 64; m <<= 1) s += __shfl_xor(s, m, 64);
    if ((tid & 63) == 0) sw[tid >> 6] = s;
    __syncthreads();
    if (tid == 0) bsum[blockIdx.x] = sw[0] + sw[1] + sw[2] + sw[3];
}

extern "C" __global__ __launch_bounds__(128)
void scan_top_kernel(int* __restrict__ bsum)
{
    __shared__ int s[128];
    int tid = threadIdx.x;
    int v = (tid < NB_SCAN) ? bsum[tid] : 0;
    s[tid] = v;
    __syncthreads();
    #pragma unroll
    for (int off = 1; off < 128; off <<= 1) {
        int t = (tid >= off) ? s[tid - off] : 0;
        __syncthreads();
        s[tid] += t;
        __syncthreads();
    }
    if (tid < NB_SCAN) bsum[tid] = s[tid] - v;
}

extern "C" __global__ __launch_bounds__(256)
void scan_final_kernel(const int* __restrict__ deg, const int* __restrict__ bsum,
                       int* __restrict__ offs, int* __restrict__ cur)
{
    __shared__ int s[256];
    int tid = threadIdx.x;
    int base = blockIdx.x * SCAN_CHUNK + tid * 4;
    int d[4];
    #pragma unroll
    for (int j = 0; j < 4; ++j) {
        int idx = base + j;
        d[j] = (idx < N_NODES) ? deg[idx] : 0;
    }
    int tot = d[0] + d[1] + d[2] + d[3];
    s[tid] = tot;
    __syncthreads();
    #pragma unroll
    for (int off = 1; off < 256; off <<= 1) {
        int t = (tid >= off) ? s[tid - off] : 0;
        __syncthreads();
        s[tid] += t;
        __syncthreads();
    }
    int b = bsum[blockIdx.x] + s[tid] - tot;
    #pragma unroll
    for (int j = 0; j < 4; ++j) {
        int idx = base + j;
        if (idx < N_NODES) { offs[idx] = b; cur[idx] = b; }
        b += d[j];
    }
}

// -----------------------------------------------------------------------------
// scatter: one record per edge at its CSR slot.
// fast: {src, w0..w4} (24 B, 3x int2 stores); slow: {src, e} (8 B)
// -----------------------------------------------------------------------------
extern "C" __global__ __launch_bounds__(256)
void scatter_kernel(const int* __restrict__ ei, const float* __restrict__ ea,
                    int* __restrict__ cur, int* __restrict__ recs, int fast)
{
    int e = blockIdx.x * 256 + threadIdx.x;
    if (e >= N_EDGES) return;
    unsigned d = (unsigned)ei[N_EDGES + e];
    unsigned s = (unsigned)ei[e];
    d = d < N_NODES ? d : (N_NODES - 1);
    s = s < N_NODES ? s : (N_NODES - 1);
    int pos = atomicAdd(&cur[d], 1);
    if (fast) {
        const float* a = ea + (size_t)e * EDGE_DIM;
        unsigned w[5];
        #pragma unroll
        for (int k = 0; k < 5; ++k) {
            float2 p = *(const float2*)&a[2 * k];
            w[k] = f2bf(p.x) | (f2bf(p.y) << 16);
        }
        int2* r = (int2*)(recs + (size_t)pos * 6);
        r[0] = make_int2((int)s, (int)w[0]);
        r[1] = make_int2((int)w[1], (int)w[2]);
        r[2] = make_int2((int)w[3], (int)w[4]);
    } else {
        ((int2*)recs)[pos] = make_int2((int)s, e);
    }
}

// per-slot message compute: 5 attr dwords (10 bf16) x 4 features + x add + relu
#define SLOT_ACC(W0, Bv, Cv, Xv, MK)                                            \
    {                                                                           \
        float m0 = bias4.x, m1 = bias4.y, m2 = bias4.z, m3 = bias4.w;           \
        unsigned wd_; float a_;                                                 \
        wd_ = (unsigned)(W0);                                                   \
        a_ = __uint_as_float(wd_ << 16);                                        \
        m0 = fmaf(a_, wc[0].x, m0); m1 = fmaf(a_, wc[0].y, m1);                 \
        m2 = fmaf(a_, wc[0].z, m2); m3 = fmaf(a_, wc[0].w, m3);                 \
        a_ = __uint_as_float(wd_ & 0xFFFF0000u);                                \
        m0 = fmaf(a_, wc[1].x, m0); m1 = fmaf(a_, wc[1].y, m1);                 \
        m2 = fmaf(a_, wc[1].z, m2); m3 = fmaf(a_, wc[1].w, m3);                 \
        wd_ = (unsigned)(Bv).x;                                                 \
        a_ = __uint_as_float(wd_ << 16);                                        \
        m0 = fmaf(a_, wc[2].x, m0); m1 = fmaf(a_, wc[2].y, m1);                 \
        m2 = fmaf(a_, wc[2].z, m2); m3 = fmaf(a_, wc[2].w, m3);                 \
        a_ = __uint_as_float(wd_ & 0xFFFF0000u);                                \
        m0 = fmaf(a_, wc[3].x, m0); m1 = fmaf(a_, wc[3].y, m1);                 \
        m2 = fmaf(a_, wc[3].z, m2); m3 = fmaf(a_, wc[3].w, m3);                 \
        wd_ = (unsigned)(Bv).y;                                                 \
        a_ = __uint_as_float(wd_ << 16);                                        \
        m0 = fmaf(a_, wc[4].x, m0); m1 = fmaf(a_, wc[4].y, m1);                 \
        m2 = fmaf(a_, wc[4].z, m2); m3 = fmaf(a_, wc[4].w, m3);                 \
        a_ = __uint_as_float(wd_ & 0xFFFF0000u);                                \
        m0 = fmaf(a_, wc[5].x, m0); m1 = fmaf(a_, wc[5].y, m1);                 \
        m2 = fmaf(a_, wc[5].z, m2); m3 = fmaf(a_, wc[5].w, m3);                 \
        wd_ = (unsigned)(Cv).x;                                                 \
        a_ = __uint_as_float(wd_ << 16);                                        \
        m0 = fmaf(a_, wc[6].x, m0); m1 = fmaf(a_, wc[6].y, m1);                 \
        m2 = fmaf(a_, wc[6].z, m2); m3 = fmaf(a_, wc[6].w, m3);                 \
        a_ = __uint_as_float(wd_ & 0xFFFF0000u);                                \
        m0 = fmaf(a_, wc[7].x, m0); m1 = fmaf(a_, wc[7].y, m1);                 \
        m2 = fmaf(a_, wc[7].z, m2); m3 = fmaf(a_, wc[7].w, m3);                 \
        wd_ = (unsigned)(Cv).y;                                                 \
        a_ = __uint_as_float(wd_ << 16);                                        \
        m0 = fmaf(a_, wc[8].x, m0); m1 = fmaf(a_, wc[8].y, m1);                 \
        m2 = fmaf(a_, wc[8].z, m2); m3 = fmaf(a_, wc[8].w, m3);                 \
        a_ = __uint_as_float(wd_ & 0xFFFF0000u);                                \
        m0 = fmaf(a_, wc[9].x, m0); m1 = fmaf(a_, wc[9].y, m1);                 \
        m2 = fmaf(a_, wc[9].z, m2); m3 = fmaf(a_, wc[9].w, m3);                 \
        float x0_ = __uint_as_float(((unsigned)(Xv).x) << 16);                  \
        float x1_ = __uint_as_float(((unsigned)(Xv).x) & 0xFFFF0000u);          \
        float x2_ = __uint_as_float(((unsigned)(Xv).y) << 16);                  \
        float x3_ = __uint_as_float(((unsigned)(Xv).y) & 0xFFFF0000u);          \
        float c0_ = fmaxf(m0 + x0_, 0.0f);                                      \
        float c1_ = fmaxf(m1 + x1_, 0.0f);                                      \
        float c2_ = fmaxf(m2 + x2_, 0.0f);                                      \
        float c3_ = fmaxf(m3 + x3_, 0.0f);                                      \
        ax += (MK) ? c0_ : 0.0f; ay += (MK) ? c1_ : 0.0f;                       \
        az += (MK) ? c2_ : 0.0f; aw += (MK) ? c3_ : 0.0f;                       \
    }

// -----------------------------------------------------------------------------
// aggregation kernel: LDS-FREE, 2 nodes per wave, quarter-wave mapping.
// Writes fp32 aggregate (x_v + sum msgs) into the OUTPUT buffer.
// -----------------------------------------------------------------------------
extern "C" __global__ __launch_bounds__(256)
void aggr_kernel(const unsigned short* __restrict__ xh,
                 const float* __restrict__ ea,
                 const float* __restrict__ We,
                 const float* __restrict__ be,
                 const int* __restrict__ offs,
                 const int* __restrict__ cur,
                 const int* __restrict__ recs,
                 float* __restrict__ aggr,
                 int fast)
{
    int tid  = threadIdx.x;
    int lane = tid & 63;
    int wv   = tid >> 6;
    int fq   = lane & 15;
    int q    = lane >> 4;

    float4 wc[EDGE_DIM];
    #pragma unroll
    for (int k = 0; k < EDGE_DIM; ++k)
        wc[k] = *(const float4*)&We[k * DIM + 4 * fq];
    float4 bias4 = *(const float4*)&be[4 * fq];

    const uint2* xq2 = (const uint2*)xh;
    const int2*  rc2 = (const int2*)recs;

    #pragma unroll 1
    for (int t = 0; t < 2; ++t) {
        int v = blockIdx.x * 8 + wv * 2 + t;
        if (v >= N_NODES) break;
        uint2 sx = xq2[(unsigned)v * 16u + (unsigned)fq];   // self row, early
        int stt = __builtin_amdgcn_readfirstlane(offs[v]);
        int end = __builtin_amdgcn_readfirstlane(cur[v]);
        float ax = 0.f, ay = 0.f, az = 0.f, aw = 0.f;
        int ng = (end - stt + 15) >> 4;
        if (fast) {
            #pragma unroll 1
            for (int g = 0; g < ng; ++g) {
                int i0e = stt + g * 16;
                int e1  = end - 1;
                int s0 = i0e + q, s1 = s0 + 4, s2 = s0 + 8, s3 = s0 + 12;
                int c0 = 3 * min(s0, e1), c1 = 3 * min(s1, e1);
                int c2 = 3 * min(s2, e1), c3 = 3 * min(s3, e1);
                int2 A0 = rc2[c0],     A1 = rc2[c1];
                int2 A2 = rc2[c2],     A3 = rc2[c3];
                int2 B0 = rc2[c0 + 1], C0 = rc2[c0 + 2];
                int2 B1 = rc2[c1 + 1], C1 = rc2[c1 + 2];
                int2 B2 = rc2[c2 + 1], C2 = rc2[c2 + 2];
                int2 B3 = rc2[c3 + 1], C3 = rc2[c3 + 2];
                unsigned u0 = (unsigned)A0.x; u0 = u0 < N_NODES ? u0 : 0u;
                unsigned u1 = (unsigned)A1.x; u1 = u1 < N_NODES ? u1 : 0u;
                unsigned u2 = (unsigned)A2.x; u2 = u2 < N_NODES ? u2 : 0u;
                unsigned u3 = (unsigned)A3.x; u3 = u3 < N_NODES ? u3 : 0u;
                uint2 X0 = xq2[u0 * 16u + (unsigned)fq];
                uint2 X1 = xq2[u1 * 16u + (unsigned)fq];
                uint2 X2 = xq2[u2 * 16u + (unsigned)fq];
                uint2 X3 = xq2[u3 * 16u + (unsigned)fq];
                SLOT_ACC(A0.y, B0, C0, X0, s0 < end);
                SLOT_ACC(A1.y, B1, C1, X1, s1 < end);
                SLOT_ACC(A2.y, B2, C2, X2, s2 < end);
                SLOT_ACC(A3.y, B3, C3, X3, s3 < end);
            }
        } else {
            #pragma unroll 1
            for (int g = 0; g < ng; ++g) {
                int i0e = stt + g * 16;
                int e1  = end - 1;
                int s0 = i0e + q, s1 = s0 + 4, s2 = s0 + 8, s3 = s0 + 12;
                int2 A0 = ((const int2*)recs)[min(s0, e1)];
                int2 A1 = ((const int2*)recs)[min(s1, e1)];
                int2 A2 = ((const int2*)recs)[min(s2, e1)];
                int2 A3 = ((const int2*)recs)[min(s3, e1)];
                unsigned u0 = (unsigned)A0.x; u0 = u0 < N_NODES ? u0 : 0u;
                unsigned u1 = (unsigned)A1.x; u1 = u1 < N_NODES ? u1 : 0u;
                unsigned u2 = (unsigned)A2.x; u2 = u2 < N_NODES ? u2 : 0u;
                unsigned u3 = (unsigned)A3.x; u3 = u3 < N_NODES ? u3 : 0u;
                uint2 X0 = xq2[u0 * 16u + (unsigned)fq];
                uint2 X1 = xq2[u1 * 16u + (unsigned)fq];
                uint2 X2 = xq2[u2 * 16u + (unsigned)fq];
                uint2 X3 = xq2[u3 * 16u + (unsigned)fq];
                #pragma unroll
                for (int p = 0; p < 4; ++p) {
                    int sl = p == 0 ? s0 : p == 1 ? s1 : p == 2 ? s2 : s3;
                    unsigned ue = (unsigned)(p == 0 ? A0.y : p == 1 ? A1.y :
                                             p == 2 ? A2.y : A3.y);
                    ue = ue < N_EDGES ? ue : 0u;
                    uint2 Xv = p == 0 ? X0 : p == 1 ? X1 : p == 2 ? X2 : X3;
                    const float* a = ea + (size_t)ue * EDGE_DIM;
                    float m0 = bias4.x, m1 = bias4.y, m2 = bias4.z, m3 = bias4.w;
                    #pragma unroll
                    for (int k = 0; k < EDGE_DIM; ++k) {
                        float av = a[k];
                        m0 = fmaf(av, wc[k].x, m0);
                        m1 = fmaf(av, wc[k].y, m1);
                        m2 = fmaf(av, wc[k].z, m2);
                        m3 = fmaf(av, wc[k].w, m3);
                    }
                    float x0_ = __uint_as_float(Xv.x << 16);
                    float x1_ = __uint_as_float(Xv.x & 0xFFFF0000u);
                    float x2_ = __uint_as_float(Xv.y << 16);
                    float x3_ = __uint_as_float(Xv.y & 0xFFFF0000u);
                    bool mk = sl < end;
                    ax += mk ? fmaxf(m0 + x0_, 0.f) : 0.f;
                    ay += mk ? fmaxf(m1 + x1_, 0.f) : 0.f;
                    az += mk ? fmaxf(m2 + x2_, 0.f) : 0.f;
                    aw += mk ? fmaxf(m3 + x3_, 0.f) : 0.f;
                }
            }
        }
        // reduce across 4 quarters
        ax += __shfl_xor(ax, 16, 64); ax += __shfl_xor(ax, 32, 64);
        ay += __shfl_xor(ay, 16, 64); ay += __shfl_xor(ay, 32, 64);
        az += __shfl_xor(az, 16, 64); az += __shfl_xor(az, 32, 64);
        aw += __shfl_xor(aw, 16, 64); aw += __shfl_xor(aw, 32, 64);
        ax += __uint_as_float(sx.x << 16);
        ay += __uint_as_float(sx.x & 0xFFFF0000u);
        az += __uint_as_float(sx.y << 16);
        aw += __uint_as_float(sx.y & 0xFFFF0000u);
        if (q == 0)
            *(float4*)&aggr[(size_t)v * DIM + 4 * fq] =
                make_float4(ax, ay, az, aw);
    }
}

// -----------------------------------------------------------------------------
// MFMA MLP: 256 threads = 4 waves, 32 nodes/wave, 128 nodes/block.
// Per wave/layer: 2x4 output tiles (16x16), K=64 -> 16 MFMA. A from fp32
// aggregate (global, L2-resident) converted to bf16 in-register; B from
// pre-packed Wh fragments; Y1 bounced through wave-private LDS [32][68] fp32.
// A/B lane map: row|col = lane&15, k = (lane>>4)*8 + [0..7].
// C/D lane map: col = lane&15, row = (lane>>4)*4 + reg  [m89 verified].
// -----------------------------------------------------------------------------
extern "C" __global__ __launch_bounds__(256)
void mlp_kernel(const unsigned* __restrict__ wh,
                const float* __restrict__ b1,
                const float* __restrict__ b2,
                float* __restrict__ out,
                float* __restrict__ sums)
{
    __shared__ __align__(16) float sY[4][32 * 68];   // 34.8 KB, wave-private
    __shared__ float sRed[4][2][DIM];                // 2 KB

    int tid  = threadIdx.x;
    int lane = tid & 63;
    int wv   = tid >> 6;
    int lr   = lane & 15;     // row (A) / col (B,D) within 16-tile
    int kh   = lane >> 4;     // k-block (A/B) / row-block (D)
    int m0   = blockIdx.x * 128 + wv * 32;

    const int4* whq = (const int4*)wh;   // fragment f, lane l -> whq[f*64+l]

    // ---- B fragments, layer 1 ----
    short8v B1[2][4];
    #pragma unroll
    for (int kb = 0; kb < 2; ++kb)
        #pragma unroll
        for (int cg = 0; cg < 4; ++cg) {
            union { int4 i; short8v s; } u;
            u.i = whq[(kb * 4 + cg) * 64 + lane];
            B1[kb][cg] = u.s;
        }

    // ---- A fragments, layer 1 (from fp32 aggregate in `out`) ----
    short8v A1[2][2];
    #pragma unroll
    for (int rg = 0; rg < 2; ++rg) {
        int row = m0 + rg * 16 + lr;
        row = row < N_NODES ? row : (N_NODES - 1);
        #pragma unroll
        for (int kb = 0; kb < 2; ++kb) {
            const float4* hp =
                (const float4*)&out[(size_t)row * DIM + kb * 32 + kh * 8];
            A1[rg][kb] = pack8(hp[0], hp[1]);
        }
    }

    // ---- GEMM1 ----
    f32x4v acc1[2][4] = {};
    #pragma unroll
    for (int rg = 0; rg < 2; ++rg)
        #pragma unroll
        for (int cg = 0; cg < 4; ++cg) {
            acc1[rg][cg] = __builtin_amdgcn_mfma_f32_16x16x32_bf16(
                A1[rg][0], B1[0][cg], acc1[rg][cg], 0, 0, 0);
            acc1[rg][cg] = __builtin_amdgcn_mfma_f32_16x16x32_bf16(
                A1[rg][1], B1[1][cg], acc1[rg][cg], 0, 0, 0);
        }

    // ---- bias1 + relu -> wave-private LDS ----
    float* Y = &sY[wv][0];
    #pragma unroll
    for (int cg = 0; cg < 4; ++cg) {
        float bb = b1[cg * 16 + lr];
        #pragma unroll
        for (int rg = 0; rg < 2; ++rg)
            #pragma unroll
            for (int i = 0; i < 4; ++i) {
                float y = fmaxf(acc1[rg][cg][i] + bb, 0.0f);
                Y[(rg * 16 + kh * 4 + i) * 68 + cg * 16 + lr] = y;
            }
    }

    // ---- B fragments, layer 2 ----
    short8v B2[2][4];
    #pragma unroll
    for (int kb = 0; kb < 2; ++kb)
        #pragma unroll
        for (int cg = 0; cg < 4; ++cg) {
            union { int4 i; short8v s; } u;
            u.i = whq[(8 + kb * 4 + cg) * 64 + lane];
            B2[kb][cg] = u.s;
        }

    // ---- A fragments, layer 2 (from LDS; same-wave RAW, compiler waits) ----
    short8v A2[2][2];
    #pragma unroll
    for (int rg = 0; rg < 2; ++rg)
        #pragma unroll
        for (int kb = 0; kb < 2; ++kb) {
            const float4* yp =
                (const float4*)&Y[(rg * 16 + lr) * 68 + kb * 32 + kh * 8];
            A2[rg][kb] = pack8(yp[0], yp[1]);
        }

    // ---- GEMM2 ----
    f32x4v acc2[2][4] = {};
    #pragma unroll
    for (int rg = 0; rg < 2; ++rg)
        #pragma unroll
        for (int cg = 0; cg < 4; ++cg) {
            acc2[rg][cg] = __builtin_amdgcn_mfma_f32_16x16x32_bf16(
                A2[rg][0], B2[0][cg], acc2[rg][cg], 0, 0, 0);
            acc2[rg][cg] = __builtin_amdgcn_mfma_f32_16x16x32_bf16(
                A2[rg][1], B2[1][cg], acc2[rg][cg], 0, 0, 0);
        }

    // ---- bias2 + relu + store + BN partials ----
    float ps[4] = {0.f, 0.f, 0.f, 0.f};
    float pq[4] = {0.f, 0.f, 0.f, 0.f};
    #pragma unroll
    for (int cg = 0; cg < 4; ++cg) {
        float bb = b2[cg * 16 + lr];
        #pragma unroll
        for (int rg = 0; rg < 2; ++rg)
            #pragma unroll
            for (int i = 0; i < 4; ++i) {
                int node = m0 + rg * 16 + kh * 4 + i;
                float r = fmaxf(acc2[rg][cg][i] + bb, 0.0f);
                if (node < N_NODES) {
                    out[(size_t)node * DIM + cg * 16 + lr] = r;
                    ps[cg] += r;
                    pq[cg] += r * r;
                }
            }
    }
    // reduce over kh groups (lanes sharing lr)
    #pragma unroll
    for (int cg = 0; cg < 4; ++cg) {
        ps[cg] += __shfl_xor(ps[cg], 16, 64);
        ps[cg] += __shfl_xor(ps[cg], 32, 64);
        pq[cg] += __shfl_xor(pq[cg], 16, 64);
        pq[cg] += __shfl_xor(pq[cg], 32, 64);
    }
    if (kh == 0) {
        #pragma unroll
        for (int cg = 0; cg < 4; ++cg) {
            sRed[wv][0][cg * 16 + lr] = ps[cg];
            sRed[wv][1][cg * 16 + lr] = pq[cg];
        }
    }
    __syncthreads();
    if (tid < 128) {
        int f = tid & 63;
        int a = tid >> 6;
        float v = sRed[0][a][f] + sRed[1][a][f] + sRed[2][a][f] + sRed[3][a][f];
        unsafeAtomicAdd(&sums[a * 64 + f], v);
    }
}

// -----------------------------------------------------------------------------
// BN apply with inline stats
// -----------------------------------------------------------------------------
extern "C" __global__ __launch_bounds__(256)
void bn_apply_kernel(float* __restrict__ out, const float* __restrict__ sums,
                     const float* __restrict__ gamma, const float* __restrict__ beta)
{
    int j = blockIdx.x * 256 + threadIdx.x;
    int f0 = (j & 15) * 4;
    float4 s1 = *(const float4*)&sums[f0];
    float4 s2 = *(const float4*)&sums[64 + f0];
    float4 gm = *(const float4*)&gamma[f0];
    float4 bt = *(const float4*)&beta[f0];
    const float inv_n = 1.0f / (float)N_NODES;
    float4 sc, sh;
    {
        float m = s1.x * inv_n; float vv = fmaf(-m, m, s2.x * inv_n);
        sc.x = gm.x * rsqrtf(vv + BN_EPS); sh.x = fmaf(-m, sc.x, bt.x);
    }
    {
        float m = s1.y * inv_n; float vv = fmaf(-m, m, s2.y * inv_n);
        sc.y = gm.y * rsqrtf(vv + BN_EPS); sh.y = fmaf(-m, sc.y, bt.y);
    }
    {
        float m = s1.z * inv_n; float vv = fmaf(-m, m, s2.z * inv_n);
        sc.z = gm.z * rsqrtf(vv + BN_EPS); sh.z = fmaf(-m, sc.z, bt.z);
    }
    {
        float m = s1.w * inv_n; float vv = fmaf(-m, m, s2.w * inv_n);
        sc.w = gm.w * rsqrtf(vv + BN_EPS); sh.w = fmaf(-m, sc.w, bt.w);
    }
    float4 v = ((float4*)out)[j];
    v.x = fmaf(v.x, sc.x, sh.x);
    v.y = fmaf(v.y, sc.y, sh.y);
    v.z = fmaf(v.z, sc.z, sh.z);
    v.w = fmaf(v.w, sc.w, sh.w);
    ((float4*)out)[j] = v;
}

extern "C" void kernel_launch(void* const* d_in, const int* in_sizes, int n_in,
                              void* d_out, int out_size, void* d_ws, size_t ws_size,
                              hipStream_t stream)
{
    const float* x     = (const float*)d_in[0];
    const int*   ei    = (const int*)  d_in[1];
    const float* ea    = (const float*)d_in[2];
    const float* We    = (const float*)d_in[3];
    const float* be    = (const float*)d_in[4];
    const float* W1    = (const float*)d_in[5];
    const float* b1    = (const float*)d_in[6];
    const float* W2    = (const float*)d_in[7];
    const float* b2    = (const float*)d_in[8];
    const float* gamma = (const float*)d_in[9];
    const float* beta  = (const float*)d_in[10];

    float* out  = (float*)d_out;
    int*   wsi  = (int*)d_ws;
    int*   deg  = wsi + DEG_OFF;
    float* sums = (float*)(wsi + SUMS_OFF_I);
    int*   offs = wsi + OFFS_OFF;
    int*   cur  = wsi + CUR_OFF;
    int*   bsum = wsi + BSUM_OFF;
    unsigned* wh = (unsigned*)(wsi + WH_OFF);
    int*   recs = wsi + REC_OFF;

    // fast mode: 24 B/edge records + xh (+16 KB Wh vs prior layout)
    size_t need_fast = ((size_t)REC_OFF + 6u * N_EDGES + (size_t)N_NODES * DIM / 2) * 4u;
    int fast = (ws_size >= need_fast) ? 1 : 0;
    int rec_ints = fast ? 6 * N_EDGES : 2 * N_EDGES;
    unsigned short* xh = (unsigned short*)(wsi + REC_OFF + rec_ints);

    // zero deg + BN sums (adjacent) in one memset
    hipMemsetAsync(wsi, 0, (size_t)(N_NODES + 256) * sizeof(int), stream);

    prep_kernel<<<2048, 256, 0, stream>>>(x, xh, ei, deg);
    scan_bsum_kernel<<<NB_SCAN, 256, 0, stream>>>(deg, bsum, W1, W2, wh);
    scan_top_kernel<<<1, 128, 0, stream>>>(bsum);
    scan_final_kernel<<<NB_SCAN, 256, 0, stream>>>(deg, bsum, offs, cur);
    scatter_kernel<<<(N_EDGES + 255) / 256, 256, 0, stream>>>(ei, ea, cur, recs, fast);

    // aggregation -> fp32 aggregate staged in `out`
    aggr_kernel<<<(N_NODES + 7) / 8, 256, 0, stream>>>(
        xh, ea, We, be, offs, cur, recs, out, fast);

    // MFMA MLP reads tile from `out`, overwrites `out`
    mlp_kernel<<<(N_NODES + 127) / 128, 256, 0, stream>>>(
        wh, b1, b2, out, sums);

    bn_apply_kernel<<<(N_NODES * DIM / 4) / 256, 256, 0, stream>>>(out, sums, gamma, beta);
}